// Round 3
// baseline (262.230 us; speedup 1.0000x reference)
//
#include <hip/hip_runtime.h>
#include <hip/hip_bf16.h>

typedef unsigned short u16;
typedef unsigned int   u32;

// Problem dims
#define NB   64
#define NTX  2048
#define ND   256
#define NL   1024
#define NMEL 80

__device__ __forceinline__ float bf2f(u16 x){
  union { u32 u; float f; } c; c.u = ((u32)x) << 16; return c.f;
}
__device__ __forceinline__ u16 f2bf(float f){
  union { float f; u32 u; } c; c.f = f;
  u32 r = (c.u + 0x7fffu + ((c.u >> 16) & 1u)) >> 16;
  return (u16)r;
}
__device__ __forceinline__ void unpack8(uint4 w, float* o){
  o[0]=bf2f((u16)(w.x&0xffffu)); o[1]=bf2f((u16)(w.x>>16));
  o[2]=bf2f((u16)(w.y&0xffffu)); o[3]=bf2f((u16)(w.y>>16));
  o[4]=bf2f((u16)(w.z&0xffffu)); o[5]=bf2f((u16)(w.z>>16));
  o[6]=bf2f((u16)(w.w&0xffffu)); o[7]=bf2f((u16)(w.w>>16));
}
__device__ __forceinline__ float sigmf(float x){ return 1.f/(1.f+__expf(-x)); }
__device__ __forceinline__ float tanhf_fast(float x){
  x = fminf(fmaxf(x, -15.f), 15.f);
  float e = __expf(2.f*x);
  return (e - 1.f) / (e + 1.f);
}
// dot of fp32 row (K4*4 elems, 16B-aligned) with fp32 LDS vector
__device__ __forceinline__ float dot_rowf(const float* __restrict__ row,
                                          const float* __restrict__ x, int K4){
  float acc = 0.f;
  for (int j = 0; j < K4; ++j){
    float4 w = *(const float4*)(row + j*4);
    const float* xp = x + j*4;
    acc += w.x*xp[0] + w.y*xp[1] + w.z*xp[2] + w.w*xp[3];
  }
  return acc;
}

// ---------------------------------------------------------------------------
// K1: front-end. One block per batch row b.
// PreNet (fc1+relu, fc2+relu), GRU-text, qp = h_text' @ tW.T, GRU-attn.
// Also writes fp32 transposed copies of h_r1,h_r2,c_r1,c_r2 for later GEMMs.
// Style branch is dead code (mels doesn't depend on it) -> skipped.
// ---------------------------------------------------------------------------
__global__ __launch_bounds__(256) void k_front(
    const float* __restrict__ prenet_in, const float* __restrict__ cv_text,
    const float* __restrict__ cv,        const float* __restrict__ h_text,
    const float* __restrict__ h_attn,
    const float* __restrict__ fc1_w, const float* __restrict__ fc1_b,
    const float* __restrict__ fc2_w, const float* __restrict__ fc2_b,
    const float* __restrict__ tWm,
    const float* __restrict__ t_wih, const float* __restrict__ t_whh,
    const float* __restrict__ t_bih, const float* __restrict__ t_bhh,
    const float* __restrict__ a_wih, const float* __restrict__ a_whh,
    const float* __restrict__ a_bih, const float* __restrict__ a_bhh,
    const float* __restrict__ h_r1,  const float* __restrict__ h_r2,
    const float* __restrict__ c_r1,  const float* __restrict__ c_r2,
    float* __restrict__ qp,   float* __restrict__ xriT,
    float* __restrict__ hr1T, float* __restrict__ hr2T,
    float* __restrict__ cr1T, float* __restrict__ cr2T)
{
  const int tid = threadIdx.x;
  const int b   = blockIdx.x;
  __shared__ float pin[80];
  __shared__ float p1[256];
  __shared__ float p2[128];
  __shared__ float xt[384], xa[384], ht[256], ha[256], htn[256];

  if (tid < 80) pin[tid] = prenet_in[b*80 + tid];
  xt[tid] = cv_text[b*ND + tid];
  xa[tid] = cv[b*ND + tid];
  ht[tid] = h_text[b*ND + tid];
  ha[tid] = h_attn[b*ND + tid];
  #pragma unroll
  for (int i = 0; i < 4; ++i){               // transposed state copies
    int j = tid + 256*i;
    hr1T[(size_t)j*NB + b] = h_r1[b*NL + j];
    hr2T[(size_t)j*NB + b] = h_r2[b*NL + j];
    cr1T[(size_t)j*NB + b] = c_r1[b*NL + j];
    cr2T[(size_t)j*NB + b] = c_r2[b*NL + j];
  }
  __syncthreads();
  // fc1: [80] -> [256], relu
  p1[tid] = fmaxf(dot_rowf(fc1_w + (size_t)tid*80, pin, 20) + fc1_b[tid], 0.f);
  __syncthreads();
  // fc2: [256] -> [128], relu
  if (tid < 128)
    p2[tid] = fmaxf(dot_rowf(fc2_w + (size_t)tid*256, p1, 64) + fc2_b[tid], 0.f);
  __syncthreads();
  if (tid < 128){ xt[256+tid] = p2[tid]; xa[256+tid] = p2[tid]; }
  __syncthreads();

  // GRU-text (d = tid)
  {
    float gir = dot_rowf(t_wih + (size_t)tid*384,       xt, 96) + t_bih[tid];
    float giz = dot_rowf(t_wih + (size_t)(256+tid)*384, xt, 96) + t_bih[256+tid];
    float gin = dot_rowf(t_wih + (size_t)(512+tid)*384, xt, 96) + t_bih[512+tid];
    float ghr = dot_rowf(t_whh + (size_t)tid*256,       ht, 64) + t_bhh[tid];
    float ghz = dot_rowf(t_whh + (size_t)(256+tid)*256, ht, 64) + t_bhh[256+tid];
    float ghn = dot_rowf(t_whh + (size_t)(512+tid)*256, ht, 64) + t_bhh[512+tid];
    float r = sigmf(gir + ghr), z = sigmf(giz + ghz);
    float nn = tanhf_fast(gin + r*ghn);
    htn[tid] = (1.f - z)*nn + z*ht[tid];
  }
  // GRU-attn (independent of GRU-text)
  {
    float gir = dot_rowf(a_wih + (size_t)tid*384,       xa, 96) + a_bih[tid];
    float giz = dot_rowf(a_wih + (size_t)(256+tid)*384, xa, 96) + a_bih[256+tid];
    float gin = dot_rowf(a_wih + (size_t)(512+tid)*384, xa, 96) + a_bih[512+tid];
    float ghr = dot_rowf(a_whh + (size_t)tid*256,       ha, 64) + a_bhh[tid];
    float ghz = dot_rowf(a_whh + (size_t)(256+tid)*256, ha, 64) + a_bhh[256+tid];
    float ghn = dot_rowf(a_whh + (size_t)(512+tid)*256, ha, 64) + a_bhh[512+tid];
    float r = sigmf(gir + ghr), z = sigmf(giz + ghz);
    float nn = tanhf_fast(gin + r*ghn);
    float han = (1.f - z)*nn + z*ha[tid];
    xriT[(size_t)(256+tid)*NB + b] = han;    // rows 256..511 of ri input
  }
  __syncthreads();
  // qp = h_text_new @ tW.T
  qp[b*ND + tid] = dot_rowf(tWm + (size_t)tid*256, htn, 64);
}

// ---------------------------------------------------------------------------
// K2: attention partial pass over encoder memory (single read of enc).
// softmax without max-subtraction (|u| <= ~4 analytically).
// Block (b, chunk of 128 t). Writes [ctx_partial(256), s_partial] per chunk.
// ---------------------------------------------------------------------------
__global__ __launch_bounds__(256) void k_attn_part(
    const float* __restrict__ enc, const float* __restrict__ qp,
    const float* __restrict__ tv,  float* __restrict__ attnP)
{
  const int tid = threadIdx.x, b = blockIdx.x, ch = blockIdx.y;
  const int wave = tid >> 6, lane = tid & 63;
  __shared__ float qpL[256], vL[256], ctxL[4][256], sL[4];
  qpL[tid] = qp[b*ND + tid];
  vL[tid]  = tv[tid];
  __syncthreads();

  const float q0 = qpL[lane*4+0], q1 = qpL[lane*4+1], q2 = qpL[lane*4+2], q3 = qpL[lane*4+3];
  const float v0 = vL[lane*4+0],  v1 = vL[lane*4+1],  v2 = vL[lane*4+2],  v3 = vL[lane*4+3];
  float cx0=0.f, cx1=0.f, cx2=0.f, cx3=0.f, sacc=0.f;
  const float* base = enc + ((size_t)b*NTX + (size_t)ch*128 + wave*32)*ND + lane*4;
  #pragma unroll 4
  for (int i = 0; i < 32; ++i){
    float4 ev = *(const float4*)(base + (size_t)i*ND);
    float e0 = ev.x, e1 = ev.y, e2 = ev.z, e3 = ev.w;
    float pp = v0*tanhf_fast(e0+q0) + v1*tanhf_fast(e1+q1)
             + v2*tanhf_fast(e2+q2) + v3*tanhf_fast(e3+q3);
    #pragma unroll
    for (int off = 1; off < 64; off <<= 1) pp += __shfl_xor(pp, off);
    float w = __expf(pp);
    sacc += w; cx0 += w*e0; cx1 += w*e1; cx2 += w*e2; cx3 += w*e3;
  }
  ctxL[wave][lane*4+0]=cx0; ctxL[wave][lane*4+1]=cx1;
  ctxL[wave][lane*4+2]=cx2; ctxL[wave][lane*4+3]=cx3;
  if (lane == 0) sL[wave] = sacc;
  __syncthreads();
  float c = ctxL[0][tid]+ctxL[1][tid]+ctxL[2][tid]+ctxL[3][tid];
  float* dst = attnP + ((size_t)b*16 + ch)*257;
  dst[tid] = c;
  if (tid == 0) dst[256] = sL[0]+sL[1]+sL[2]+sL[3];
}

// K3: combine 16 chunk partials -> cv_new, write as rows 0..255 of xriT
__global__ __launch_bounds__(256) void k_attn_red(
    const float* __restrict__ attnP, float* __restrict__ xriT)
{
  const int tid = threadIdx.x, b = blockIdx.x;
  float c = 0.f, s = 0.f;
  for (int ch = 0; ch < 16; ++ch){
    const float* src = attnP + ((size_t)b*16 + ch)*257;
    c += src[tid]; s += src[256];
  }
  xriT[(size_t)tid*NB + b] = c / s;
}

// ---------------------------------------------------------------------------
// K4: generic K-split GEMM  C[split][n][b] = W[n,:kchunk] @ X_T[:, b]
// W fp32 [N,K] row-major (converted to bf16 in LDS at staging);
// X fp32 transposed [K][64]; 8b x 8n register tile, fp32 accumulate.
// Up to 2 fused (independent) GEMMs via blockIdx.z.
// ---------------------------------------------------------------------------
struct GDesc { const float* W; const float* X; float* C; int N, K, S, ntiles; };
struct GBatch { GDesc g[2]; };

__global__ __launch_bounds__(256) void k_gemm(GBatch batch){
  GDesc d = batch.g[blockIdx.z];
  const int tile = blockIdx.x;  if (tile >= d.ntiles) return;
  const int split = blockIdx.y; if (split >= d.S) return;
  const int tid = threadIdx.x;
  __shared__ u16  Ws[64*264];
  __shared__ float Xs[64*68];
  const int n0 = tile*256;
  const int kchunk = d.K / d.S;        // multiple of 64
  const int k0 = split * kchunk;
  const int bq = tid & 7, nq = tid >> 3;
  float acc[8][8];
  for (int i = 0; i < 8; ++i)
    for (int j = 0; j < 8; ++j)
      acc[i][j] = 0.f;

  for (int kb = 0; kb < kchunk; kb += 64){
    const int kbase = k0 + kb;
    { // stage W: thread = one n-row, 64 k (fp32 -> bf16, transposed Ws[k][n])
      const float* wr = d.W + (size_t)(n0 + tid)*d.K + kbase;
      #pragma unroll
      for (int j = 0; j < 8; ++j){
        float4 wa = *(const float4*)(wr + j*8);
        float4 wb = *(const float4*)(wr + j*8 + 4);
        int kk = j*8;
        Ws[(kk+0)*264 + tid] = f2bf(wa.x);
        Ws[(kk+1)*264 + tid] = f2bf(wa.y);
        Ws[(kk+2)*264 + tid] = f2bf(wa.z);
        Ws[(kk+3)*264 + tid] = f2bf(wa.w);
        Ws[(kk+4)*264 + tid] = f2bf(wb.x);
        Ws[(kk+5)*264 + tid] = f2bf(wb.y);
        Ws[(kk+6)*264 + tid] = f2bf(wb.z);
        Ws[(kk+7)*264 + tid] = f2bf(wb.w);
      }
    }
    { // stage X chunk [64k][64b]
      const int k = tid >> 2, q = tid & 3;
      const float* xr = d.X + (size_t)(kbase + k)*NB + q*16;
      float4 a0 = *(const float4*)(xr+0);
      float4 a1 = *(const float4*)(xr+4);
      float4 a2 = *(const float4*)(xr+8);
      float4 a3 = *(const float4*)(xr+12);
      float* xs = &Xs[k*68 + q*16];
      *(float4*)(xs+0)=a0; *(float4*)(xs+4)=a1; *(float4*)(xs+8)=a2; *(float4*)(xs+12)=a3;
    }
    __syncthreads();
    #pragma unroll 4
    for (int k = 0; k < 64; ++k){
      float4 xa = *(const float4*)&Xs[k*68 + bq*8];
      float4 xb = *(const float4*)&Xs[k*68 + bq*8 + 4];
      uint4 wv  = *(const uint4*)&Ws[k*264 + nq*8];
      float wf[8]; unpack8(wv, wf);
      float xf[8] = {xa.x,xa.y,xa.z,xa.w,xb.x,xb.y,xb.z,xb.w};
      #pragma unroll
      for (int i = 0; i < 8; ++i)
        #pragma unroll
        for (int j = 0; j < 8; ++j)
          acc[i][j] += wf[i]*xf[j];
    }
    __syncthreads();
  }
  #pragma unroll
  for (int i = 0; i < 8; ++i){
    int n = n0 + nq*8 + i;
    float* dst = d.C + ((size_t)split * d.N + n) * NB + bq*8;
    float4 o0 = {acc[i][0],acc[i][1],acc[i][2],acc[i][3]};
    float4 o1 = {acc[i][4],acc[i][5],acc[i][6],acc[i][7]};
    *(float4*)(dst)   = o0;
    *(float4*)(dst+4) = o1;
  }
}

// K5: x0T = sum of 8 ri partial slabs + ri_b
__global__ __launch_bounds__(256) void k_finx(
    const float* __restrict__ riP, const float* __restrict__ ri_b,
    float* __restrict__ x0T)
{
  const int idx = blockIdx.x*256 + threadIdx.x;  // 65536 total
  const int j = idx >> 6, b = idx & 63;
  float a = ri_b[j];
  #pragma unroll
  for (int s = 0; s < 8; ++s) a += riP[((size_t)s*NL + j)*NB + b];
  x0T[(size_t)j*NB + b] = a;
}

// K6: LSTM cell: sum gate partials, apply nonlinearity, x_out = x_in + h'
__global__ __launch_bounds__(256) void k_cell(
    const float* __restrict__ giP, const float* __restrict__ ghP,
    const float* __restrict__ bih, const float* __restrict__ bhh,
    const float* __restrict__ cT,
    const float* __restrict__ xinT, float* __restrict__ xoutT)
{
  const int idx = blockIdx.x*256 + threadIdx.x;  // 65536
  const int j = idx >> 6, b = idx & 63;
  float g[4] = {0.f,0.f,0.f,0.f};
  #pragma unroll
  for (int s = 0; s < 8; ++s){
    #pragma unroll
    for (int gg = 0; gg < 4; ++gg){
      size_t off = ((size_t)s*4096 + gg*NL + j)*NB + b;
      g[gg] += giP[off] + ghP[off];
    }
  }
  #pragma unroll
  for (int gg = 0; gg < 4; ++gg)
    g[gg] += bih[gg*NL + j] + bhh[gg*NL + j];
  float ii = sigmf(g[0]), ff = sigmf(g[1]);
  float gv = tanhf_fast(g[2]), oo = sigmf(g[3]);
  float cc = ff * cT[idx] + ii * gv;
  float hh = oo * tanhf_fast(cc);
  xoutT[idx] = xinT[idx] + hh;
}

// K7: mel projection — only rows with col%20 < 2 of mp_w are needed.
__global__ __launch_bounds__(256) void k_mels(
    const float* __restrict__ x2T, const float* __restrict__ mp_w,
    float* __restrict__ out)
{
  const int tid = threadIdx.x, b = blockIdx.x;
  __shared__ float xL[NL];
  #pragma unroll
  for (int i = 0; i < 4; ++i){
    int j = tid + 256*i;
    xL[j] = x2T[(size_t)j*NB + b];
  }
  __syncthreads();
  if (tid < 160){
    int m = tid >> 1, r = tid & 1;
    float acc = dot_rowf(mp_w + (size_t)(m*20 + r)*NL, xL, 256);
    out[b*160 + tid] = acc;
  }
}

// ---------------------------------------------------------------------------
extern "C" void kernel_launch(void* const* d_in, const int* in_sizes, int n_in,
                              void* d_out, int out_size, void* d_ws, size_t ws_size,
                              hipStream_t stream)
{
  (void)in_sizes; (void)n_in; (void)out_size; (void)ws_size;
  const float* enc     = (const float*)d_in[0];
  const float* pre_in  = (const float*)d_in[2];
  const float* h_text  = (const float*)d_in[3];
  const float* h_attn  = (const float*)d_in[5];
  const float* h_r1    = (const float*)d_in[6];
  const float* h_r2    = (const float*)d_in[7];
  const float* c_r1    = (const float*)d_in[8];
  const float* c_r2    = (const float*)d_in[9];
  const float* cv_text = (const float*)d_in[10];
  const float* cv      = (const float*)d_in[12];
  const float* fc1_w   = (const float*)d_in[13];
  const float* fc1_b   = (const float*)d_in[14];
  const float* fc2_w   = (const float*)d_in[15];
  const float* fc2_b   = (const float*)d_in[16];
  const float* tWm     = (const float*)d_in[17];
  const float* tv      = (const float*)d_in[18];
  const float* t_wih   = (const float*)d_in[21];
  const float* t_whh   = (const float*)d_in[22];
  const float* t_bih   = (const float*)d_in[23];
  const float* t_bhh   = (const float*)d_in[24];
  const float* a_wih   = (const float*)d_in[29];
  const float* a_whh   = (const float*)d_in[30];
  const float* a_bih   = (const float*)d_in[31];
  const float* a_bhh   = (const float*)d_in[32];
  const float* ri_w    = (const float*)d_in[33];
  const float* ri_b    = (const float*)d_in[34];
  const float* l1_wih  = (const float*)d_in[35];
  const float* l1_whh  = (const float*)d_in[36];
  const float* l1_bih  = (const float*)d_in[37];
  const float* l1_bhh  = (const float*)d_in[38];
  const float* l2_wih  = (const float*)d_in[39];
  const float* l2_whh  = (const float*)d_in[40];
  const float* l2_bih  = (const float*)d_in[41];
  const float* l2_bhh  = (const float*)d_in[42];
  const float* mp_w    = (const float*)d_in[43];

  // workspace layout (floats) — total ~22 MB
  float* ws    = (float*)d_ws;
  float* qp    = ws;                    // 64*256
  float* xriT  = qp    + 16384;         // 512*64
  float* hr1T  = xriT  + 32768;         // 1024*64
  float* hr2T  = hr1T  + 65536;
  float* cr1T  = hr2T  + 65536;
  float* cr2T  = cr1T  + 65536;
  float* attnP = cr2T  + 65536;         // 64*16*257
  float* x0T   = attnP + 263168;        // 1024*64
  float* x1T   = x0T   + 65536;
  float* x2T   = x1T   + 65536;
  float* riP   = x2T   + 65536;         // 8*1024*64
  float* giP   = riP   + 524288;        // 8*4096*64
  float* ghP   = giP   + 2097152;       // 8*4096*64

  k_front<<<64, 256, 0, stream>>>(pre_in, cv_text, cv, h_text, h_attn,
      fc1_w, fc1_b, fc2_w, fc2_b, tWm,
      t_wih, t_whh, t_bih, t_bhh, a_wih, a_whh, a_bih, a_bhh,
      h_r1, h_r2, c_r1, c_r2,
      qp, xriT, hr1T, hr2T, cr1T, cr2T);

  k_attn_part<<<dim3(64,16), 256, 0, stream>>>(enc, qp, tv, attnP);
  k_attn_red<<<64, 256, 0, stream>>>(attnP, xriT);

  { GBatch gb; gb.g[0].W=ri_w; gb.g[0].X=xriT; gb.g[0].C=riP;
    gb.g[0].N=1024; gb.g[0].K=512; gb.g[0].S=8; gb.g[0].ntiles=4;
    gb.g[1]=gb.g[0];
    k_gemm<<<dim3(4,8,1), 256, 0, stream>>>(gb); }
  k_finx<<<256, 256, 0, stream>>>(riP, ri_b, x0T);

  { GBatch gb;
    gb.g[0].W=l1_wih; gb.g[0].X=x0T;  gb.g[0].C=giP;
    gb.g[0].N=4096; gb.g[0].K=1024; gb.g[0].S=8; gb.g[0].ntiles=16;
    gb.g[1].W=l1_whh; gb.g[1].X=hr1T; gb.g[1].C=ghP;
    gb.g[1].N=4096; gb.g[1].K=1024; gb.g[1].S=8; gb.g[1].ntiles=16;
    k_gemm<<<dim3(16,8,2), 256, 0, stream>>>(gb); }
  k_cell<<<256, 256, 0, stream>>>(giP, ghP, l1_bih, l1_bhh, cr1T, x0T, x1T);

  { GBatch gb;
    gb.g[0].W=l2_wih; gb.g[0].X=x1T;  gb.g[0].C=giP;
    gb.g[0].N=4096; gb.g[0].K=1024; gb.g[0].S=8; gb.g[0].ntiles=16;
    gb.g[1].W=l2_whh; gb.g[1].X=hr2T; gb.g[1].C=ghP;
    gb.g[1].N=4096; gb.g[1].K=1024; gb.g[1].S=8; gb.g[1].ntiles=16;
    k_gemm<<<dim3(16,8,2), 256, 0, stream>>>(gb); }
  k_cell<<<256, 256, 0, stream>>>(giP, ghP, l2_bih, l2_bhh, cr2T, x1T, x2T);

  k_mels<<<64, 256, 0, stream>>>(x2T, mp_w, (float*)d_out);
}

// Round 4
// 171.725 us; speedup vs baseline: 1.5270x; 1.5270x over previous
//
#include <hip/hip_runtime.h>
#include <hip/hip_bf16.h>

typedef unsigned short u16;
typedef unsigned int   u32;

// Problem dims
#define NB   64
#define NTX  2048
#define ND   256
#define NL   1024
#define NMEL 80

__device__ __forceinline__ float bf2f(u16 x){
  union { u32 u; float f; } c; c.u = ((u32)x) << 16; return c.f;
}
__device__ __forceinline__ u16 f2bf(float f){
  union { float f; u32 u; } c; c.f = f;
  u32 r = (c.u + 0x7fffu + ((c.u >> 16) & 1u)) >> 16;
  return (u16)r;
}
__device__ __forceinline__ void unpack8(uint4 w, float* o){
  o[0]=bf2f((u16)(w.x&0xffffu)); o[1]=bf2f((u16)(w.x>>16));
  o[2]=bf2f((u16)(w.y&0xffffu)); o[3]=bf2f((u16)(w.y>>16));
  o[4]=bf2f((u16)(w.z&0xffffu)); o[5]=bf2f((u16)(w.z>>16));
  o[6]=bf2f((u16)(w.w&0xffffu)); o[7]=bf2f((u16)(w.w>>16));
}
__device__ __forceinline__ float sigmf(float x){ return 1.f/(1.f+__expf(-x)); }
__device__ __forceinline__ float tanhf_fast(float x){
  x = fminf(fmaxf(x, -15.f), 15.f);
  float e = __expf(2.f*x);
  return (e - 1.f) / (e + 1.f);
}
__device__ __forceinline__ float dot_rowf(const float* __restrict__ row,
                                          const float* __restrict__ x, int K4){
  float acc = 0.f;
  for (int j = 0; j < K4; ++j){
    float4 w = *(const float4*)(row + j*4);
    const float* xp = x + j*4;
    acc += w.x*xp[0] + w.y*xp[1] + w.z*xp[2] + w.w*xp[3];
  }
  return acc;
}

// ---------------------------------------------------------------------------
// F1: blocks 0..79 -> tiled transposes of small state arrays into [dim][64];
//     blocks 80..143 -> fc1 (batch-on-lanes: wave = out neuron, lane = b).
// ---------------------------------------------------------------------------
__global__ __launch_bounds__(256) void k_pre1(
    const float* __restrict__ cv_text, const float* __restrict__ cv,
    const float* __restrict__ h_text,  const float* __restrict__ h_attn,
    const float* __restrict__ h_r1, const float* __restrict__ h_r2,
    const float* __restrict__ c_r1, const float* __restrict__ c_r2,
    const float* __restrict__ prenet_in,
    const float* __restrict__ fc1_w, const float* __restrict__ fc1_b,
    float* __restrict__ cvtT, float* __restrict__ cvT,
    float* __restrict__ htT,  float* __restrict__ haT,
    float* __restrict__ hr1T, float* __restrict__ hr2T,
    float* __restrict__ cr1T, float* __restrict__ cr2T,
    float* __restrict__ p1T)
{
  __shared__ float ld[64][65];
  const int blk = blockIdx.x, tid = threadIdx.x;
  if (blk < 80){
    const float* src; float* dst; int cols, c0;
    if (blk < 16){
      int a = blk >> 2; c0 = (blk & 3)*64; cols = 256;
      src = (a==0)?cv_text:(a==1)?cv:(a==2)?h_text:h_attn;
      dst = (a==0)?cvtT:(a==1)?cvT:(a==2)?htT:haT;
    } else {
      int t2 = blk - 16; int a = t2 >> 4; c0 = (t2 & 15)*64; cols = 1024;
      src = (a==0)?h_r1:(a==1)?h_r2:(a==2)?c_r1:c_r2;
      dst = (a==0)?hr1T:(a==1)?hr2T:(a==2)?cr1T:cr2T;
    }
    const int r = tid >> 2, q = tid & 3;
    #pragma unroll
    for (int i = 0; i < 4; ++i){
      float4 v = *(const float4*)(src + (size_t)r*cols + c0 + q*16 + i*4);
      ld[r][q*16+i*4+0] = v.x; ld[r][q*16+i*4+1] = v.y;
      ld[r][q*16+i*4+2] = v.z; ld[r][q*16+i*4+3] = v.w;
    }
    __syncthreads();
    const int cc = tid >> 2;
    #pragma unroll
    for (int i = 0; i < 4; ++i){
      int b0 = q*16 + i*4;
      float4 o = { ld[b0+0][cc], ld[b0+1][cc], ld[b0+2][cc], ld[b0+3][cc] };
      *(float4*)(dst + (size_t)(c0+cc)*64 + b0) = o;
    }
  } else {
    const int wave = tid >> 6, lane = tid & 63;
    const int n = (blk - 80)*4 + wave;          // 0..255
    float acc = fc1_b[n];
    const float* wr = fc1_w + (size_t)n*80;
    const float* xr = prenet_in + (size_t)lane*80;
    #pragma unroll
    for (int k = 0; k < 80; k += 4){
      float4 w = *(const float4*)(wr + k);
      acc += w.x*xr[k] + w.y*xr[k+1] + w.z*xr[k+2] + w.w*xr[k+3];
    }
    p1T[n*64 + lane] = fmaxf(acc, 0.f);
  }
}

// F2: fc2 (wave = out neuron n<128, lane = b), inputs p1T coalesced.
__global__ __launch_bounds__(256) void k_pre2(
    const float* __restrict__ p1T,
    const float* __restrict__ fc2_w, const float* __restrict__ fc2_b,
    float* __restrict__ p2T)
{
  const int tid = threadIdx.x, wave = tid >> 6, lane = tid & 63;
  const int n = blockIdx.x*4 + wave;            // 0..127
  float acc = fc2_b[n];
  const float* wr = fc2_w + (size_t)n*256;
  for (int k = 0; k < 256; k += 4){
    float4 w = *(const float4*)(wr + k);
    acc += w.x*p1T[(k+0)*64+lane] + w.y*p1T[(k+1)*64+lane]
         + w.z*p1T[(k+2)*64+lane] + w.w*p1T[(k+3)*64+lane];
  }
  p2T[n*64 + lane] = fmaxf(acc, 0.f);
}

// ---------------------------------------------------------------------------
// F3: both GRU cells, batch-on-lanes. blocks 0..63: text GRU (-> htnT),
// blocks 64..127: attn GRU (-> xriT rows 256..511). wave = out dim d.
// ---------------------------------------------------------------------------
__global__ __launch_bounds__(256) void k_gru(
    const float* __restrict__ t_wih, const float* __restrict__ t_whh,
    const float* __restrict__ t_bih, const float* __restrict__ t_bhh,
    const float* __restrict__ a_wih, const float* __restrict__ a_whh,
    const float* __restrict__ a_bih, const float* __restrict__ a_bhh,
    const float* __restrict__ cvtT, const float* __restrict__ cvT,
    const float* __restrict__ htT,  const float* __restrict__ haT,
    const float* __restrict__ p2T,
    float* __restrict__ htnT, float* __restrict__ xriT)
{
  const int tid = threadIdx.x, wave = tid >> 6, lane = tid & 63;
  const int isA = (blockIdx.x >= 64);
  const int d = (blockIdx.x & 63)*4 + wave;     // 0..255
  const float* wih = isA ? a_wih : t_wih;
  const float* whh = isA ? a_whh : t_whh;
  const float* bih = isA ? a_bih : t_bih;
  const float* bhh = isA ? a_bhh : t_bhh;
  const float* xT  = isA ? cvT   : cvtT;        // rows 0..255 of GRU input
  const float* hT  = isA ? haT   : htT;

  float gir = bih[d],     giz = bih[256+d], gin = bih[512+d];
  float ghr = bhh[d],     ghz = bhh[256+d], ghn = bhh[512+d];
  const float* wr = wih + (size_t)d*384;
  const float* wz = wih + (size_t)(256+d)*384;
  const float* wn = wih + (size_t)(512+d)*384;
  for (int k = 0; k < 256; k += 4){
    float4 ar = *(const float4*)(wr + k);
    float4 az = *(const float4*)(wz + k);
    float4 an = *(const float4*)(wn + k);
    float x0 = xT[(k+0)*64+lane], x1 = xT[(k+1)*64+lane];
    float x2 = xT[(k+2)*64+lane], x3 = xT[(k+3)*64+lane];
    gir += ar.x*x0 + ar.y*x1 + ar.z*x2 + ar.w*x3;
    giz += az.x*x0 + az.y*x1 + az.z*x2 + az.w*x3;
    gin += an.x*x0 + an.y*x1 + an.z*x2 + an.w*x3;
  }
  for (int k = 0; k < 128; k += 4){
    float4 ar = *(const float4*)(wr + 256 + k);
    float4 az = *(const float4*)(wz + 256 + k);
    float4 an = *(const float4*)(wn + 256 + k);
    float x0 = p2T[(k+0)*64+lane], x1 = p2T[(k+1)*64+lane];
    float x2 = p2T[(k+2)*64+lane], x3 = p2T[(k+3)*64+lane];
    gir += ar.x*x0 + ar.y*x1 + ar.z*x2 + ar.w*x3;
    giz += az.x*x0 + az.y*x1 + az.z*x2 + az.w*x3;
    gin += an.x*x0 + an.y*x1 + an.z*x2 + an.w*x3;
  }
  const float* vr = whh + (size_t)d*256;
  const float* vz = whh + (size_t)(256+d)*256;
  const float* vn = whh + (size_t)(512+d)*256;
  for (int k = 0; k < 256; k += 4){
    float4 ar = *(const float4*)(vr + k);
    float4 az = *(const float4*)(vz + k);
    float4 an = *(const float4*)(vn + k);
    float h0 = hT[(k+0)*64+lane], h1 = hT[(k+1)*64+lane];
    float h2 = hT[(k+2)*64+lane], h3 = hT[(k+3)*64+lane];
    ghr += ar.x*h0 + ar.y*h1 + ar.z*h2 + ar.w*h3;
    ghz += az.x*h0 + az.y*h1 + az.z*h2 + az.w*h3;
    ghn += an.x*h0 + an.y*h1 + an.z*h2 + an.w*h3;
  }
  float hd = hT[d*64 + lane];
  float r  = sigmf(gir + ghr), z = sigmf(giz + ghz);
  float nn = tanhf_fast(gin + r*ghn);
  float hnew = (1.f - z)*nn + z*hd;
  if (isA) xriT[(size_t)(256+d)*64 + lane] = hnew;
  else     htnT[(size_t)d*64 + lane]       = hnew;
}

// F4: qp[b][d] = sum_k tW[d][k] * htn[b][k]  (wave = d, lane = b)
__global__ __launch_bounds__(256) void k_qp(
    const float* __restrict__ tWm, const float* __restrict__ htnT,
    float* __restrict__ qp)
{
  const int tid = threadIdx.x, wave = tid >> 6, lane = tid & 63;
  const int d = blockIdx.x*4 + wave;            // 0..255
  float acc = 0.f;
  const float* wr = tWm + (size_t)d*256;
  for (int k = 0; k < 256; k += 4){
    float4 w = *(const float4*)(wr + k);
    acc += w.x*htnT[(k+0)*64+lane] + w.y*htnT[(k+1)*64+lane]
         + w.z*htnT[(k+2)*64+lane] + w.w*htnT[(k+3)*64+lane];
  }
  qp[lane*ND + d] = acc;
}

// ---------------------------------------------------------------------------
// K2: attention partial pass over encoder memory (single read of enc).
// ---------------------------------------------------------------------------
__global__ __launch_bounds__(256) void k_attn_part(
    const float* __restrict__ enc, const float* __restrict__ qp,
    const float* __restrict__ tv,  float* __restrict__ attnP)
{
  const int tid = threadIdx.x, b = blockIdx.x, ch = blockIdx.y;
  const int wave = tid >> 6, lane = tid & 63;
  __shared__ float qpL[256], vL[256], ctxL[4][256], sL[4];
  qpL[tid] = qp[b*ND + tid];
  vL[tid]  = tv[tid];
  __syncthreads();

  const float q0 = qpL[lane*4+0], q1 = qpL[lane*4+1], q2 = qpL[lane*4+2], q3 = qpL[lane*4+3];
  const float v0 = vL[lane*4+0],  v1 = vL[lane*4+1],  v2 = vL[lane*4+2],  v3 = vL[lane*4+3];
  float cx0=0.f, cx1=0.f, cx2=0.f, cx3=0.f, sacc=0.f;
  const float* base = enc + ((size_t)b*NTX + (size_t)ch*128 + wave*32)*ND + lane*4;
  #pragma unroll 4
  for (int i = 0; i < 32; ++i){
    float4 ev = *(const float4*)(base + (size_t)i*ND);
    float e0 = ev.x, e1 = ev.y, e2 = ev.z, e3 = ev.w;
    float pp = v0*tanhf_fast(e0+q0) + v1*tanhf_fast(e1+q1)
             + v2*tanhf_fast(e2+q2) + v3*tanhf_fast(e3+q3);
    #pragma unroll
    for (int off = 1; off < 64; off <<= 1) pp += __shfl_xor(pp, off);
    float w = __expf(pp);
    sacc += w; cx0 += w*e0; cx1 += w*e1; cx2 += w*e2; cx3 += w*e3;
  }
  ctxL[wave][lane*4+0]=cx0; ctxL[wave][lane*4+1]=cx1;
  ctxL[wave][lane*4+2]=cx2; ctxL[wave][lane*4+3]=cx3;
  if (lane == 0) sL[wave] = sacc;
  __syncthreads();
  float c = ctxL[0][tid]+ctxL[1][tid]+ctxL[2][tid]+ctxL[3][tid];
  float* dst = attnP + ((size_t)b*16 + ch)*257;
  dst[tid] = c;
  if (tid == 0) dst[256] = sL[0]+sL[1]+sL[2]+sL[3];
}

// K3: combine 16 chunk partials -> cv_new, write as rows 0..255 of xriT
__global__ __launch_bounds__(256) void k_attn_red(
    const float* __restrict__ attnP, float* __restrict__ xriT)
{
  const int tid = threadIdx.x, b = blockIdx.x;
  float c = 0.f, s = 0.f;
  for (int ch = 0; ch < 16; ++ch){
    const float* src = attnP + ((size_t)b*16 + ch)*257;
    c += src[tid]; s += src[256];
  }
  xriT[(size_t)tid*NB + b] = c / s;
}

// ---------------------------------------------------------------------------
// K4: generic K-split GEMM  C[split][n][b] = W[n,:kchunk] @ X_T[:, b]
// W fp32 [N,K] row-major (converted to bf16 in LDS at staging);
// X fp32 transposed [K][64]; 8b x 8n register tile, fp32 accumulate.
// ---------------------------------------------------------------------------
struct GDesc { const float* W; const float* X; float* C; int N, K, S, ntiles; };
struct GBatch { GDesc g[2]; };

__global__ __launch_bounds__(256) void k_gemm(GBatch batch){
  GDesc d = batch.g[blockIdx.z];
  const int tile = blockIdx.x;  if (tile >= d.ntiles) return;
  const int split = blockIdx.y; if (split >= d.S) return;
  const int tid = threadIdx.x;
  __shared__ u16  Ws[64*264];
  __shared__ float Xs[64*68];
  const int n0 = tile*256;
  const int kchunk = d.K / d.S;        // multiple of 64
  const int k0 = split * kchunk;
  const int bq = tid & 7, nq = tid >> 3;
  float acc[8][8];
  for (int i = 0; i < 8; ++i)
    for (int j = 0; j < 8; ++j)
      acc[i][j] = 0.f;

  for (int kb = 0; kb < kchunk; kb += 64){
    const int kbase = k0 + kb;
    { // stage W: thread = one n-row, 64 k (fp32 -> bf16, transposed Ws[k][n])
      const float* wr = d.W + (size_t)(n0 + tid)*d.K + kbase;
      #pragma unroll
      for (int j = 0; j < 8; ++j){
        float4 wa = *(const float4*)(wr + j*8);
        float4 wb = *(const float4*)(wr + j*8 + 4);
        int kk = j*8;
        Ws[(kk+0)*264 + tid] = f2bf(wa.x);
        Ws[(kk+1)*264 + tid] = f2bf(wa.y);
        Ws[(kk+2)*264 + tid] = f2bf(wa.z);
        Ws[(kk+3)*264 + tid] = f2bf(wa.w);
        Ws[(kk+4)*264 + tid] = f2bf(wb.x);
        Ws[(kk+5)*264 + tid] = f2bf(wb.y);
        Ws[(kk+6)*264 + tid] = f2bf(wb.z);
        Ws[(kk+7)*264 + tid] = f2bf(wb.w);
      }
    }
    { // stage X chunk [64k][64b]
      const int k = tid >> 2, q = tid & 3;
      const float* xr = d.X + (size_t)(kbase + k)*NB + q*16;
      float4 a0 = *(const float4*)(xr+0);
      float4 a1 = *(const float4*)(xr+4);
      float4 a2 = *(const float4*)(xr+8);
      float4 a3 = *(const float4*)(xr+12);
      float* xs = &Xs[k*68 + q*16];
      *(float4*)(xs+0)=a0; *(float4*)(xs+4)=a1; *(float4*)(xs+8)=a2; *(float4*)(xs+12)=a3;
    }
    __syncthreads();
    #pragma unroll 4
    for (int k = 0; k < 64; ++k){
      float4 xa = *(const float4*)&Xs[k*68 + bq*8];
      float4 xb = *(const float4*)&Xs[k*68 + bq*8 + 4];
      uint4 wv  = *(const uint4*)&Ws[k*264 + nq*8];
      float wf[8]; unpack8(wv, wf);
      float xf[8] = {xa.x,xa.y,xa.z,xa.w,xb.x,xb.y,xb.z,xb.w};
      #pragma unroll
      for (int i = 0; i < 8; ++i)
        #pragma unroll
        for (int j = 0; j < 8; ++j)
          acc[i][j] += wf[i]*xf[j];
    }
    __syncthreads();
  }
  #pragma unroll
  for (int i = 0; i < 8; ++i){
    int n = n0 + nq*8 + i;
    float* dst = d.C + ((size_t)split * d.N + n) * NB + bq*8;
    float4 o0 = {acc[i][0],acc[i][1],acc[i][2],acc[i][3]};
    float4 o1 = {acc[i][4],acc[i][5],acc[i][6],acc[i][7]};
    *(float4*)(dst)   = o0;
    *(float4*)(dst+4) = o1;
  }
}

// K5: x0T = sum of 8 ri partial slabs + ri_b
__global__ __launch_bounds__(256) void k_finx(
    const float* __restrict__ riP, const float* __restrict__ ri_b,
    float* __restrict__ x0T)
{
  const int idx = blockIdx.x*256 + threadIdx.x;  // 65536 total
  const int j = idx >> 6, b = idx & 63;
  float a = ri_b[j];
  #pragma unroll
  for (int s = 0; s < 8; ++s) a += riP[((size_t)s*NL + j)*NB + b];
  x0T[(size_t)j*NB + b] = a;
}

// K6: LSTM cell: sum gate partials, apply nonlinearity, x_out = x_in + h'
__global__ __launch_bounds__(256) void k_cell(
    const float* __restrict__ giP, const float* __restrict__ ghP,
    const float* __restrict__ bih, const float* __restrict__ bhh,
    const float* __restrict__ cT,
    const float* __restrict__ xinT, float* __restrict__ xoutT)
{
  const int idx = blockIdx.x*256 + threadIdx.x;  // 65536
  const int j = idx >> 6, b = idx & 63;
  float g[4] = {0.f,0.f,0.f,0.f};
  #pragma unroll
  for (int s = 0; s < 8; ++s){
    #pragma unroll
    for (int gg = 0; gg < 4; ++gg){
      size_t off = ((size_t)s*4096 + gg*NL + j)*NB + b;
      g[gg] += giP[off] + ghP[off];
    }
  }
  #pragma unroll
  for (int gg = 0; gg < 4; ++gg)
    g[gg] += bih[gg*NL + j] + bhh[gg*NL + j];
  float ii = sigmf(g[0]), ff = sigmf(g[1]);
  float gv = tanhf_fast(g[2]), oo = sigmf(g[3]);
  float cc = ff * cT[idx] + ii * gv;
  float hh = oo * tanhf_fast(cc);
  xoutT[idx] = xinT[idx] + hh;
}

// K7: mel projection — only rows with col%20 < 2 of mp_w are needed.
__global__ __launch_bounds__(256) void k_mels(
    const float* __restrict__ x2T, const float* __restrict__ mp_w,
    float* __restrict__ out)
{
  const int tid = threadIdx.x, b = blockIdx.x;
  __shared__ float xL[NL];
  #pragma unroll
  for (int i = 0; i < 4; ++i){
    int j = tid + 256*i;
    xL[j] = x2T[(size_t)j*NB + b];
  }
  __syncthreads();
  if (tid < 160){
    int m = tid >> 1, r = tid & 1;
    float acc = dot_rowf(mp_w + (size_t)(m*20 + r)*NL, xL, 256);
    out[b*160 + tid] = acc;
  }
}

// ---------------------------------------------------------------------------
extern "C" void kernel_launch(void* const* d_in, const int* in_sizes, int n_in,
                              void* d_out, int out_size, void* d_ws, size_t ws_size,
                              hipStream_t stream)
{
  (void)in_sizes; (void)n_in; (void)out_size; (void)ws_size;
  const float* enc     = (const float*)d_in[0];
  const float* pre_in  = (const float*)d_in[2];
  const float* h_text  = (const float*)d_in[3];
  const float* h_attn  = (const float*)d_in[5];
  const float* h_r1    = (const float*)d_in[6];
  const float* h_r2    = (const float*)d_in[7];
  const float* c_r1    = (const float*)d_in[8];
  const float* c_r2    = (const float*)d_in[9];
  const float* cv_text = (const float*)d_in[10];
  const float* cv      = (const float*)d_in[12];
  const float* fc1_w   = (const float*)d_in[13];
  const float* fc1_b   = (const float*)d_in[14];
  const float* fc2_w   = (const float*)d_in[15];
  const float* fc2_b   = (const float*)d_in[16];
  const float* tWm     = (const float*)d_in[17];
  const float* tv      = (const float*)d_in[18];
  const float* t_wih   = (const float*)d_in[21];
  const float* t_whh   = (const float*)d_in[22];
  const float* t_bih   = (const float*)d_in[23];
  const float* t_bhh   = (const float*)d_in[24];
  const float* a_wih   = (const float*)d_in[29];
  const float* a_whh   = (const float*)d_in[30];
  const float* a_bih   = (const float*)d_in[31];
  const float* a_bhh   = (const float*)d_in[32];
  const float* ri_w    = (const float*)d_in[33];
  const float* ri_b    = (const float*)d_in[34];
  const float* l1_wih  = (const float*)d_in[35];
  const float* l1_whh  = (const float*)d_in[36];
  const float* l1_bih  = (const float*)d_in[37];
  const float* l1_bhh  = (const float*)d_in[38];
  const float* l2_wih  = (const float*)d_in[39];
  const float* l2_whh  = (const float*)d_in[40];
  const float* l2_bih  = (const float*)d_in[41];
  const float* l2_bhh  = (const float*)d_in[42];
  const float* mp_w    = (const float*)d_in[43];

  // workspace layout (floats) — same 22.2 MB footprint as the passing R3 run
  float* ws    = (float*)d_ws;
  float* qp    = ws;                    // 64*256
  float* xriT  = qp    + 16384;         // 512*64
  float* hr1T  = xriT  + 32768;         // 1024*64
  float* hr2T  = hr1T  + 65536;
  float* cr1T  = hr2T  + 65536;
  float* cr2T  = cr1T  + 65536;
  float* attnP = cr2T  + 65536;         // 64*16*257
  float* x0T   = attnP + 263168;        // 1024*64
  float* x1T   = x0T   + 65536;
  float* x2T   = x1T   + 65536;
  float* riP   = x2T   + 65536;         // 8*1024*64
  float* giP   = riP   + 524288;        // 8*4096*64
  float* ghP   = giP   + 2097152;       // 8*4096*64

  // front-end temps aliased into giP (dead before giP is written)
  float* cvtT  = giP;                   // 256*64
  float* cvT   = giP + 16384;
  float* htT   = giP + 32768;
  float* haT   = giP + 49152;
  float* htnT  = giP + 65536;
  float* p1T   = giP + 81920;           // 256*64
  float* p2T   = giP + 98304;           // 128*64

  k_pre1<<<144, 256, 0, stream>>>(cv_text, cv, h_text, h_attn,
      h_r1, h_r2, c_r1, c_r2, pre_in, fc1_w, fc1_b,
      cvtT, cvT, htT, haT, hr1T, hr2T, cr1T, cr2T, p1T);
  k_pre2<<<32, 256, 0, stream>>>(p1T, fc2_w, fc2_b, p2T);
  k_gru<<<128, 256, 0, stream>>>(t_wih, t_whh, t_bih, t_bhh,
      a_wih, a_whh, a_bih, a_bhh, cvtT, cvT, htT, haT, p2T, htnT, xriT);
  k_qp<<<64, 256, 0, stream>>>(tWm, htnT, qp);

  k_attn_part<<<dim3(64,16), 256, 0, stream>>>(enc, qp, tv, attnP);
  k_attn_red<<<64, 256, 0, stream>>>(attnP, xriT);

  { GBatch gb; gb.g[0].W=ri_w; gb.g[0].X=xriT; gb.g[0].C=riP;
    gb.g[0].N=1024; gb.g[0].K=512; gb.g[0].S=8; gb.g[0].ntiles=4;
    gb.g[1]=gb.g[0];
    k_gemm<<<dim3(4,8,1), 256, 0, stream>>>(gb); }
  k_finx<<<256, 256, 0, stream>>>(riP, ri_b, x0T);

  { GBatch gb;
    gb.g[0].W=l1_wih; gb.g[0].X=x0T;  gb.g[0].C=giP;
    gb.g[0].N=4096; gb.g[0].K=1024; gb.g[0].S=8; gb.g[0].ntiles=16;
    gb.g[1].W=l1_whh; gb.g[1].X=hr1T; gb.g[1].C=ghP;
    gb.g[1].N=4096; gb.g[1].K=1024; gb.g[1].S=8; gb.g[1].ntiles=16;
    k_gemm<<<dim3(16,8,2), 256, 0, stream>>>(gb); }
  k_cell<<<256, 256, 0, stream>>>(giP, ghP, l1_bih, l1_bhh, cr1T, x0T, x1T);

  { GBatch gb;
    gb.g[0].W=l2_wih; gb.g[0].X=x1T;  gb.g[0].C=giP;
    gb.g[0].N=4096; gb.g[0].K=1024; gb.g[0].S=8; gb.g[0].ntiles=16;
    gb.g[1].W=l2_whh; gb.g[1].X=hr2T; gb.g[1].C=ghP;
    gb.g[1].N=4096; gb.g[1].K=1024; gb.g[1].S=8; gb.g[1].ntiles=16;
    k_gemm<<<dim3(16,8,2), 256, 0, stream>>>(gb); }
  k_cell<<<256, 256, 0, stream>>>(giP, ghP, l2_bih, l2_bhh, cr2T, x1T, x2T);

  k_mels<<<64, 256, 0, stream>>>(x2T, mp_w, (float*)d_out);
}

// Round 5
// 134.619 us; speedup vs baseline: 1.9479x; 1.2756x over previous
//
#include <hip/hip_runtime.h>
#include <hip/hip_bf16.h>

typedef unsigned short u16;
typedef unsigned int   u32;
typedef __attribute__((ext_vector_type(8))) short bf16x8;
typedef __attribute__((ext_vector_type(4))) float f32x4;

#define NB   64
#define NTX  2048
#define ND   256
#define NL   1024

__device__ __forceinline__ u16 f2bf(float f){
  union { float f; u32 u; } c; c.f = f;
  return (u16)((c.u + 0x7fffu + ((c.u >> 16) & 1u)) >> 16);
}
__device__ __forceinline__ u32 pk2(float a, float b){
  return (u32)f2bf(a) | ((u32)f2bf(b) << 16);
}
__device__ __forceinline__ float sigmf(float x){ return 1.f/(1.f+__expf(-x)); }
__device__ __forceinline__ float tanhf_fast(float x){
  x = fminf(fmaxf(x, -15.f), 15.f);
  float e = __expf(2.f*x);
  return (e - 1.f) / (e + 1.f);
}
__device__ __forceinline__ float dot_rowf(const float* __restrict__ row,
                                          const float* __restrict__ x, int K4){
  float acc = 0.f;
  for (int j = 0; j < K4; ++j){
    float4 w = *(const float4*)(row + j*4);
    const float* xp = x + j*4;
    acc += w.x*xp[0] + w.y*xp[1] + w.z*xp[2] + w.w*xp[3];
  }
  return acc;
}

// ---------------------------------------------------------------------------
// F1: blocks 0..15 -> tiled transposes of [64][256] states into [256][64];
//     blocks 16..79 -> fc1 (batch-on-lanes: wave = out neuron, lane = b).
// ---------------------------------------------------------------------------
__global__ __launch_bounds__(256) void k_pre1(
    const float* __restrict__ cv_text, const float* __restrict__ cv,
    const float* __restrict__ h_text,  const float* __restrict__ h_attn,
    const float* __restrict__ prenet_in,
    const float* __restrict__ fc1_w, const float* __restrict__ fc1_b,
    float* __restrict__ cvtT, float* __restrict__ cvT,
    float* __restrict__ htT,  float* __restrict__ haT,
    float* __restrict__ p1T)
{
  __shared__ float ld[64][65];
  const int blk = blockIdx.x, tid = threadIdx.x;
  if (blk < 16){
    int a = blk >> 2; int c0 = (blk & 3)*64;
    const float* src = (a==0)?cv_text:(a==1)?cv:(a==2)?h_text:h_attn;
    float* dst = (a==0)?cvtT:(a==1)?cvT:(a==2)?htT:haT;
    const int r = tid >> 2, q = tid & 3;
    #pragma unroll
    for (int i = 0; i < 4; ++i){
      float4 v = *(const float4*)(src + (size_t)r*256 + c0 + q*16 + i*4);
      ld[r][q*16+i*4+0] = v.x; ld[r][q*16+i*4+1] = v.y;
      ld[r][q*16+i*4+2] = v.z; ld[r][q*16+i*4+3] = v.w;
    }
    __syncthreads();
    const int cc = tid >> 2;
    #pragma unroll
    for (int i = 0; i < 4; ++i){
      int b0 = q*16 + i*4;
      float4 o = { ld[b0+0][cc], ld[b0+1][cc], ld[b0+2][cc], ld[b0+3][cc] };
      *(float4*)(dst + (size_t)(c0+cc)*64 + b0) = o;
    }
  } else {
    const int wave = tid >> 6, lane = tid & 63;
    const int n = (blk - 16)*4 + wave;          // 0..255
    float acc = fc1_b[n];
    const float* wr = fc1_w + (size_t)n*80;
    const float* xr = prenet_in + (size_t)lane*80;
    #pragma unroll
    for (int k = 0; k < 80; k += 4){
      float4 w = *(const float4*)(wr + k);
      acc += w.x*xr[k] + w.y*xr[k+1] + w.z*xr[k+2] + w.w*xr[k+3];
    }
    p1T[n*64 + lane] = fmaxf(acc, 0.f);
  }
}

// F2: fc2 (wave = out neuron n<128, lane = b)
__global__ __launch_bounds__(256) void k_pre2(
    const float* __restrict__ p1T,
    const float* __restrict__ fc2_w, const float* __restrict__ fc2_b,
    float* __restrict__ p2T)
{
  const int tid = threadIdx.x, wave = tid >> 6, lane = tid & 63;
  const int n = blockIdx.x*4 + wave;            // 0..127
  float acc = fc2_b[n];
  const float* wr = fc2_w + (size_t)n*256;
  for (int k = 0; k < 256; k += 4){
    float4 w = *(const float4*)(wr + k);
    acc += w.x*p1T[(k+0)*64+lane] + w.y*p1T[(k+1)*64+lane]
         + w.z*p1T[(k+2)*64+lane] + w.w*p1T[(k+3)*64+lane];
  }
  p2T[n*64 + lane] = fmaxf(acc, 0.f);
}

// F3: both GRU cells, batch-on-lanes. blocks 0..63: text GRU (-> htnT),
// blocks 64..127: attn GRU (-> xri[b][256+d], natural layout).
__global__ __launch_bounds__(256) void k_gru(
    const float* __restrict__ t_wih, const float* __restrict__ t_whh,
    const float* __restrict__ t_bih, const float* __restrict__ t_bhh,
    const float* __restrict__ a_wih, const float* __restrict__ a_whh,
    const float* __restrict__ a_bih, const float* __restrict__ a_bhh,
    const float* __restrict__ cvtT, const float* __restrict__ cvT,
    const float* __restrict__ htT,  const float* __restrict__ haT,
    const float* __restrict__ p2T,
    float* __restrict__ htnT, float* __restrict__ xri)
{
  const int tid = threadIdx.x, wave = tid >> 6, lane = tid & 63;
  const int isA = (blockIdx.x >= 64);
  const int d = (blockIdx.x & 63)*4 + wave;     // 0..255
  const float* wih = isA ? a_wih : t_wih;
  const float* whh = isA ? a_whh : t_whh;
  const float* bih = isA ? a_bih : t_bih;
  const float* bhh = isA ? a_bhh : t_bhh;
  const float* xT  = isA ? cvT   : cvtT;
  const float* hT  = isA ? haT   : htT;

  float gir = bih[d],     giz = bih[256+d], gin = bih[512+d];
  float ghr = bhh[d],     ghz = bhh[256+d], ghn = bhh[512+d];
  const float* wr = wih + (size_t)d*384;
  const float* wz = wih + (size_t)(256+d)*384;
  const float* wn = wih + (size_t)(512+d)*384;
  for (int k = 0; k < 256; k += 4){
    float4 ar = *(const float4*)(wr + k);
    float4 az = *(const float4*)(wz + k);
    float4 an = *(const float4*)(wn + k);
    float x0 = xT[(k+0)*64+lane], x1 = xT[(k+1)*64+lane];
    float x2 = xT[(k+2)*64+lane], x3 = xT[(k+3)*64+lane];
    gir += ar.x*x0 + ar.y*x1 + ar.z*x2 + ar.w*x3;
    giz += az.x*x0 + az.y*x1 + az.z*x2 + az.w*x3;
    gin += an.x*x0 + an.y*x1 + an.z*x2 + an.w*x3;
  }
  for (int k = 0; k < 128; k += 4){
    float4 ar = *(const float4*)(wr + 256 + k);
    float4 az = *(const float4*)(wz + 256 + k);
    float4 an = *(const float4*)(wn + 256 + k);
    float x0 = p2T[(k+0)*64+lane], x1 = p2T[(k+1)*64+lane];
    float x2 = p2T[(k+2)*64+lane], x3 = p2T[(k+3)*64+lane];
    gir += ar.x*x0 + ar.y*x1 + ar.z*x2 + ar.w*x3;
    giz += az.x*x0 + az.y*x1 + az.z*x2 + az.w*x3;
    gin += an.x*x0 + an.y*x1 + an.z*x2 + an.w*x3;
  }
  const float* vr = whh + (size_t)d*256;
  const float* vz = whh + (size_t)(256+d)*256;
  const float* vn = whh + (size_t)(512+d)*256;
  for (int k = 0; k < 256; k += 4){
    float4 ar = *(const float4*)(vr + k);
    float4 az = *(const float4*)(vz + k);
    float4 an = *(const float4*)(vn + k);
    float h0 = hT[(k+0)*64+lane], h1 = hT[(k+1)*64+lane];
    float h2 = hT[(k+2)*64+lane], h3 = hT[(k+3)*64+lane];
    ghr += ar.x*h0 + ar.y*h1 + ar.z*h2 + ar.w*h3;
    ghz += az.x*h0 + az.y*h1 + az.z*h2 + az.w*h3;
    ghn += an.x*h0 + an.y*h1 + an.z*h2 + an.w*h3;
  }
  float hd = hT[d*64 + lane];
  float r  = sigmf(gir + ghr), z = sigmf(giz + ghz);
  float nn = tanhf_fast(gin + r*ghn);
  float hnew = (1.f - z)*nn + z*hd;
  if (isA) xri[(size_t)lane*512 + 256 + d] = hnew;
  else     htnT[(size_t)d*64 + lane]       = hnew;
}

// F4: qp[b][d]
__global__ __launch_bounds__(256) void k_qp(
    const float* __restrict__ tWm, const float* __restrict__ htnT,
    float* __restrict__ qp)
{
  const int tid = threadIdx.x, wave = tid >> 6, lane = tid & 63;
  const int d = blockIdx.x*4 + wave;
  float acc = 0.f;
  const float* wr = tWm + (size_t)d*256;
  for (int k = 0; k < 256; k += 4){
    float4 w = *(const float4*)(wr + k);
    acc += w.x*htnT[(k+0)*64+lane] + w.y*htnT[(k+1)*64+lane]
         + w.z*htnT[(k+2)*64+lane] + w.w*htnT[(k+3)*64+lane];
  }
  qp[lane*ND + d] = acc;
}

// ---------------------------------------------------------------------------
// K2: attention partial pass (single read of enc), softmax w/o max-sub.
// ---------------------------------------------------------------------------
__global__ __launch_bounds__(256) void k_attn_part(
    const float* __restrict__ enc, const float* __restrict__ qp,
    const float* __restrict__ tv,  float* __restrict__ attnP)
{
  const int tid = threadIdx.x, b = blockIdx.x, ch = blockIdx.y;
  const int wave = tid >> 6, lane = tid & 63;
  __shared__ float qpL[256], vL[256], ctxL[4][256], sL[4];
  qpL[tid] = qp[b*ND + tid];
  vL[tid]  = tv[tid];
  __syncthreads();

  const float q0 = qpL[lane*4+0], q1 = qpL[lane*4+1], q2 = qpL[lane*4+2], q3 = qpL[lane*4+3];
  const float v0 = vL[lane*4+0],  v1 = vL[lane*4+1],  v2 = vL[lane*4+2],  v3 = vL[lane*4+3];
  float cx0=0.f, cx1=0.f, cx2=0.f, cx3=0.f, sacc=0.f;
  const float* base = enc + ((size_t)b*NTX + (size_t)ch*128 + wave*32)*ND + lane*4;
  #pragma unroll 4
  for (int i = 0; i < 32; ++i){
    float4 ev = *(const float4*)(base + (size_t)i*ND);
    float e0 = ev.x, e1 = ev.y, e2 = ev.z, e3 = ev.w;
    float pp = v0*tanhf_fast(e0+q0) + v1*tanhf_fast(e1+q1)
             + v2*tanhf_fast(e2+q2) + v3*tanhf_fast(e3+q3);
    #pragma unroll
    for (int off = 1; off < 64; off <<= 1) pp += __shfl_xor(pp, off);
    float w = __expf(pp);
    sacc += w; cx0 += w*e0; cx1 += w*e1; cx2 += w*e2; cx3 += w*e3;
  }
  ctxL[wave][lane*4+0]=cx0; ctxL[wave][lane*4+1]=cx1;
  ctxL[wave][lane*4+2]=cx2; ctxL[wave][lane*4+3]=cx3;
  if (lane == 0) sL[wave] = sacc;
  __syncthreads();
  float c = ctxL[0][tid]+ctxL[1][tid]+ctxL[2][tid]+ctxL[3][tid];
  float* dst = attnP + ((size_t)b*16 + ch)*257;
  dst[tid] = c;
  if (tid == 0) dst[256] = sL[0]+sL[1]+sL[2]+sL[3];
}

// K3: combine partials -> xri[b][0..255] (natural layout)
__global__ __launch_bounds__(256) void k_attn_red(
    const float* __restrict__ attnP, float* __restrict__ xri)
{
  const int tid = threadIdx.x, b = blockIdx.x;
  float c = 0.f, s = 0.f;
  for (int ch = 0; ch < 16; ++ch){
    const float* src = attnP + ((size_t)b*16 + ch)*257;
    c += src[tid]; s += src[256];
  }
  xri[(size_t)b*512 + tid] = c / s;
}

// ---------------------------------------------------------------------------
// MFMA GEMMs. D[b][n] = X[64][K]_bf16 @ W[N][K]^T_bf16, fp32 accum.
// A-frag: lane -> X[b0+(l&15)][k0+(l>>4)*8 + i]; B-frag: W[n0+(l&15)][same k]
// D: row b = b0+(l>>4)*4+r, col n = n0+(l&15).
// ---------------------------------------------------------------------------

// ri projection: x0[64][1024] = xri[64][512] @ ri_w^T + ri_b
__global__ __launch_bounds__(256) void k_mm_ri(
    const float* __restrict__ xri, const float* __restrict__ ri_w,
    const float* __restrict__ ri_b, float* __restrict__ x0)
{
  __shared__ u16 Xs[64*520];
  __shared__ float Rs[4][4][64][4];
  const int tid = threadIdx.x, lane = tid & 63, w = tid >> 6;
  const int n0 = blockIdx.x * 16;
  { // stage xri -> bf16 LDS [64][520]
    const int b = tid >> 2, q = tid & 3;
    #pragma unroll
    for (int st = 0; st < 4; ++st){
      const int k = st*128 + q*32;
      const float* src = xri + (size_t)b*512 + k;
      uint4* dst = (uint4*)&Xs[b*520 + k];
      #pragma unroll
      for (int i = 0; i < 4; ++i){
        float4 va = *(const float4*)(src + i*8);
        float4 vb = *(const float4*)(src + i*8 + 4);
        uint4 o = { pk2(va.x,va.y), pk2(va.z,va.w), pk2(vb.x,vb.y), pk2(vb.z,vb.w) };
        dst[i] = o;
      }
    }
  }
  __syncthreads();
  f32x4 acc[4];
  #pragma unroll
  for (int i = 0; i < 4; ++i) acc[i] = (f32x4){0.f,0.f,0.f,0.f};
  const int nrow = n0 + (lane & 15);
  const float* wr = ri_w + (size_t)nrow*512 + w*128 + (lane >> 4)*8;
  const u16* xs = &Xs[(lane & 15)*520 + w*128 + (lane >> 4)*8];
  #pragma unroll
  for (int t = 0; t < 4; ++t){
    float4 wa = *(const float4*)(wr + t*32);
    float4 wb = *(const float4*)(wr + t*32 + 4);
    union { bf16x8 v; uint4 u; } bf;
    bf.u.x = pk2(wa.x,wa.y); bf.u.y = pk2(wa.z,wa.w);
    bf.u.z = pk2(wb.x,wb.y); bf.u.w = pk2(wb.z,wb.w);
    #pragma unroll
    for (int fb = 0; fb < 4; ++fb){
      union { bf16x8 v; uint4 u; } af;
      af.u = *(const uint4*)(xs + fb*16*520 + t*32);
      acc[fb] = __builtin_amdgcn_mfma_f32_16x16x32_bf16(af.v, bf.v, acc[fb], 0, 0, 0);
    }
  }
  #pragma unroll
  for (int fb = 0; fb < 4; ++fb)
    #pragma unroll
    for (int r = 0; r < 4; ++r) Rs[w][fb][lane][r] = acc[fb][r];
  __syncthreads();
  { // reduce 4 wave-partials; wave handles fb = w
    const int n = n0 + (lane & 15);
    const float bias = ri_b[n];
    #pragma unroll
    for (int r = 0; r < 4; ++r){
      float v = Rs[0][w][lane][r] + Rs[1][w][lane][r]
              + Rs[2][w][lane][r] + Rs[3][w][lane][r];
      int b = w*16 + (lane >> 4)*4 + r;
      x0[(size_t)b*1024 + n] = v + bias;
    }
  }
}

// LSTM gate partials: P[s][b][g*1024+j]; s: {ih lo, ih hi, hh lo, hh hi}
__global__ __launch_bounds__(256) void k_mm_lstm(
    const float* __restrict__ Wih, const float* __restrict__ Whh,
    const float* __restrict__ xin, const float* __restrict__ hin,
    float* __restrict__ P)
{
  __shared__ u16 Xs[64*520];
  const int tid = threadIdx.x, lane = tid & 63, g = tid >> 6;
  const int j0 = blockIdx.x * 16, s = blockIdx.y;
  const float* W = (s < 2) ? Wih : Whh;
  const float* X = (s < 2) ? xin : hin;
  const int kbase = (s & 1) * 512;
  { // stage X[:, kbase..kbase+512) -> bf16 LDS
    const int b = tid >> 2, q = tid & 3;
    #pragma unroll
    for (int st = 0; st < 4; ++st){
      const int k = st*128 + q*32;
      const float* src = X + (size_t)b*1024 + kbase + k;
      uint4* dst = (uint4*)&Xs[b*520 + k];
      #pragma unroll
      for (int i = 0; i < 4; ++i){
        float4 va = *(const float4*)(src + i*8);
        float4 vb = *(const float4*)(src + i*8 + 4);
        uint4 o = { pk2(va.x,va.y), pk2(va.z,va.w), pk2(vb.x,vb.y), pk2(vb.z,vb.w) };
        dst[i] = o;
      }
    }
  }
  __syncthreads();
  f32x4 acc[4];
  #pragma unroll
  for (int i = 0; i < 4; ++i) acc[i] = (f32x4){0.f,0.f,0.f,0.f};
  const int nrow = g*1024 + j0 + (lane & 15);
  const float* wr = W + (size_t)nrow*1024 + kbase + (lane >> 4)*8;
  const u16* xs = &Xs[(lane & 15)*520 + (lane >> 4)*8];
  #pragma unroll 2
  for (int t = 0; t < 16; ++t){
    float4 wa = *(const float4*)(wr + t*32);
    float4 wb = *(const float4*)(wr + t*32 + 4);
    union { bf16x8 v; uint4 u; } bf;
    bf.u.x = pk2(wa.x,wa.y); bf.u.y = pk2(wa.z,wa.w);
    bf.u.z = pk2(wb.x,wb.y); bf.u.w = pk2(wb.z,wb.w);
    #pragma unroll
    for (int fb = 0; fb < 4; ++fb){
      union { bf16x8 v; uint4 u; } af;
      af.u = *(const uint4*)(xs + fb*16*520 + t*32);
      acc[fb] = __builtin_amdgcn_mfma_f32_16x16x32_bf16(af.v, bf.v, acc[fb], 0, 0, 0);
    }
  }
  const int jc = j0 + (lane & 15);
  #pragma unroll
  for (int fb = 0; fb < 4; ++fb){
    const int b = fb*16 + (lane >> 4)*4;
    #pragma unroll
    for (int r = 0; r < 4; ++r)
      P[((size_t)(s*64 + b + r))*4096 + g*1024 + jc] = acc[fb][r];
  }
}

// LSTM cell: combine 4 partial slabs, nonlinearity, residual.
__global__ __launch_bounds__(256) void k_cell2(
    const float* __restrict__ P,
    const float* __restrict__ bih, const float* __restrict__ bhh,
    const float* __restrict__ c_in,
    const float* __restrict__ xin, float* __restrict__ xout)
{
  const int idx = blockIdx.x*256 + threadIdx.x;   // 65536 = 64b * 1024j
  const int b = idx >> 10, j = idx & 1023;
  float g[4];
  #pragma unroll
  for (int gg = 0; gg < 4; ++gg){
    float a = bih[gg*1024 + j] + bhh[gg*1024 + j];
    #pragma unroll
    for (int s = 0; s < 4; ++s)
      a += P[((size_t)(s*64 + b))*4096 + gg*1024 + j];
    g[gg] = a;
  }
  float ii = sigmf(g[0]), ff = sigmf(g[1]);
  float gv = tanhf_fast(g[2]), oo = sigmf(g[3]);
  float cc = ff * c_in[idx] + ii * gv;
  float hh = oo * tanhf_fast(cc);
  xout[idx] = xin[idx] + hh;
}

// K7: mel projection — only rows with col%20 < 2 of mp_w are needed.
__global__ __launch_bounds__(256) void k_mels(
    const float* __restrict__ x2, const float* __restrict__ mp_w,
    float* __restrict__ out)
{
  const int tid = threadIdx.x, b = blockIdx.x;
  __shared__ float xL[NL];
  #pragma unroll
  for (int i = 0; i < 4; ++i){
    int j = tid + 256*i;
    xL[j] = x2[(size_t)b*NL + j];
  }
  __syncthreads();
  if (tid < 160){
    int m = tid >> 1, r = tid & 1;
    float acc = dot_rowf(mp_w + (size_t)(m*20 + r)*NL, xL, 256);
    out[b*160 + tid] = acc;
  }
}

// ---------------------------------------------------------------------------
extern "C" void kernel_launch(void* const* d_in, const int* in_sizes, int n_in,
                              void* d_out, int out_size, void* d_ws, size_t ws_size,
                              hipStream_t stream)
{
  (void)in_sizes; (void)n_in; (void)out_size; (void)ws_size;
  const float* enc     = (const float*)d_in[0];
  const float* pre_in  = (const float*)d_in[2];
  const float* h_text  = (const float*)d_in[3];
  const float* h_attn  = (const float*)d_in[5];
  const float* h_r1    = (const float*)d_in[6];
  const float* h_r2    = (const float*)d_in[7];
  const float* c_r1    = (const float*)d_in[8];
  const float* c_r2    = (const float*)d_in[9];
  const float* cv_text = (const float*)d_in[10];
  const float* cv      = (const float*)d_in[12];
  const float* fc1_w   = (const float*)d_in[13];
  const float* fc1_b   = (const float*)d_in[14];
  const float* fc2_w   = (const float*)d_in[15];
  const float* fc2_b   = (const float*)d_in[16];
  const float* tWm     = (const float*)d_in[17];
  const float* tv      = (const float*)d_in[18];
  const float* t_wih   = (const float*)d_in[21];
  const float* t_whh   = (const float*)d_in[22];
  const float* t_bih   = (const float*)d_in[23];
  const float* t_bhh   = (const float*)d_in[24];
  const float* a_wih   = (const float*)d_in[29];
  const float* a_whh   = (const float*)d_in[30];
  const float* a_bih   = (const float*)d_in[31];
  const float* a_bhh   = (const float*)d_in[32];
  const float* ri_w    = (const float*)d_in[33];
  const float* ri_b    = (const float*)d_in[34];
  const float* l1_wih  = (const float*)d_in[35];
  const float* l1_whh  = (const float*)d_in[36];
  const float* l1_bih  = (const float*)d_in[37];
  const float* l1_bhh  = (const float*)d_in[38];
  const float* l2_wih  = (const float*)d_in[39];
  const float* l2_whh  = (const float*)d_in[40];
  const float* l2_bih  = (const float*)d_in[41];
  const float* l2_bhh  = (const float*)d_in[42];
  const float* mp_w    = (const float*)d_in[43];

  // workspace layout (floats), ~6.2 MB
  float* ws    = (float*)d_ws;
  float* qp    = ws;                    // 64*256
  float* xri   = qp    + 16384;         // [64][512]
  float* attnP = xri   + 32768;         // 64*16*257
  float* x0    = attnP + 263168;        // [64][1024]
  float* x1    = x0    + 65536;
  float* x2    = x1    + 65536;
  float* P     = x2    + 65536;         // [4][64][4096]

  // front temps alias P (dead before P written)
  float* cvtT  = P;                     // [256][64]
  float* cvT   = P + 16384;
  float* htT   = P + 32768;
  float* haT   = P + 49152;
  float* htnT  = P + 65536;
  float* p1T   = P + 81920;             // [256][64]
  float* p2T   = P + 98304;             // [128][64]

  k_pre1<<<80, 256, 0, stream>>>(cv_text, cv, h_text, h_attn,
      pre_in, fc1_w, fc1_b, cvtT, cvT, htT, haT, p1T);
  k_pre2<<<32, 256, 0, stream>>>(p1T, fc2_w, fc2_b, p2T);
  k_gru<<<128, 256, 0, stream>>>(t_wih, t_whh, t_bih, t_bhh,
      a_wih, a_whh, a_bih, a_bhh, cvtT, cvT, htT, haT, p2T, htnT, xri);
  k_qp<<<64, 256, 0, stream>>>(tWm, htnT, qp);

  k_attn_part<<<dim3(64,16), 256, 0, stream>>>(enc, qp, tv, attnP);
  k_attn_red<<<64, 256, 0, stream>>>(attnP, xri);

  k_mm_ri<<<64, 256, 0, stream>>>(xri, ri_w, ri_b, x0);

  k_mm_lstm<<<dim3(64,4), 256, 0, stream>>>(l1_wih, l1_whh, x0, h_r1, P);
  k_cell2<<<256, 256, 0, stream>>>(P, l1_bih, l1_bhh, c_r1, x0, x1);

  k_mm_lstm<<<dim3(64,4), 256, 0, stream>>>(l2_wih, l2_whh, x1, h_r2, P);
  k_cell2<<<256, 256, 0, stream>>>(P, l2_bih, l2_bhh, c_r2, x1, x2);

  k_mels<<<64, 256, 0, stream>>>(x2, mp_w, (float*)d_out);
}